// Round 19
// baseline (305.511 us; speedup 1.0000x reference)
//
#include <hip/hip_runtime.h>
#include <hip/hip_bf16.h>
#include <stdint.h>

#define BTOT 4096
#define RR   64
#define DIMD 128

typedef short s16x8 __attribute__((ext_vector_type(8)));
typedef float f32x4 __attribute__((ext_vector_type(4)));

__device__ __forceinline__ unsigned short f2bf(float x) {
  __hip_bfloat16 h = __float2bfloat16(x);
  return __builtin_bit_cast(unsigned short, h);
}
__device__ __forceinline__ unsigned int pk2(float lo, float hi) {
  return ((unsigned int)f2bf(hi) << 16) | (unsigned int)f2bf(lo);
}
__device__ __forceinline__ float bflo(unsigned int u) {
  return __builtin_bit_cast(float, u << 16);
}
__device__ __forceinline__ float bfhi(unsigned int u) {
  return __builtin_bit_cast(float, u & 0xFFFF0000u);
}

// global -> LDS direct load, 16B per lane, no VGPR transit
#define GLD16(gsrc, ldst)                                                   \
  __builtin_amdgcn_global_load_lds(                                         \
      (const __attribute__((address_space(1))) void*)(gsrc),                \
      (__attribute__((address_space(3))) void*)(ldst), 16, 0, 0)

// ---------------------------------------------------------------------------
// Pre-kernel: qproj[b,k] = sum_d query_r[b,d]*W1[k,128+d] + b1[k]  (fp32),
// offset_emb passthrough, and blocks 0/1 emit PERMUTED+swizzled bf16 copies
// of W1a / W2 into ws. d-permutation pi(s) = 32*(s>>5) + 16*((s>>2)&1) +
// 4*((s>>3)&3) + (s&3); bank-XOR: addr = k*128 + (s ^ ((k&7)<<3)).
// [layout verified: R16/R17 passed absmax 0.5]
// ---------------------------------------------------------------------------
__global__ __launch_bounds__(256) void prep_kernel(
    const float* __restrict__ W1, const float* __restrict__ b1,
    const float* __restrict__ query_r, const float* __restrict__ W2,
    const float* __restrict__ offset_emb,
    float* __restrict__ qproj, unsigned short* __restrict__ w1a_t,
    unsigned short* __restrict__ w2_t, float* __restrict__ out)
{
  __shared__ float w1b[128 * 132];   // +4 pad
  __shared__ float qrs[256];
  const int tid = threadIdx.x;

  { // offset_emb passthrough (1 float4 per thread; 512 blocks cover 4096x128)
    const size_t ob = (size_t)blockIdx.x * 8 * DIMD + (size_t)tid * 4;
    *reinterpret_cast<float4*>(out + (size_t)BTOT * DIMD + ob) =
        *reinterpret_cast<const float4*>(offset_emb + ob);
  }
  { // stage W1b fp32 into padded LDS
    const int k = tid >> 1, d0 = (tid & 1) * 64;
    const float* src = W1 + k * 256 + 128 + d0;
    float* dst = &w1b[k * 132 + d0];
    #pragma unroll
    for (int i = 0; i < 64; i += 4)
      *reinterpret_cast<float4*>(dst + i) = *reinterpret_cast<const float4*>(src + i);
  }
  if (blockIdx.x < 2) { // permuted + swizzled bf16 weight tables
    const float* Wsrc = (blockIdx.x == 0) ? W1 : W2;
    unsigned short* dstw = (blockIdx.x == 0) ? w1a_t : w2_t;
    const int stride = (blockIdx.x == 0) ? 256 : 128;
    for (int i = tid; i < 128 * 128; i += 256) {
      const int k = i >> 7, s = i & 127;
      const int d = 32 * (s >> 5) + 16 * ((s >> 2) & 1) + 4 * ((s >> 3) & 3) + (s & 3);
      dstw[k * 128 + (s ^ ((k & 7) << 3))] = f2bf(Wsrc[k * stride + d]);
    }
  }
  __syncthreads();

  const int b0 = blockIdx.x * 8;
  const int k = tid & 127, bh = tid >> 7;
  for (int p = 0; p < 4; ++p) {
    const int b = b0 + p * 2;
    qrs[tid] = query_r[(size_t)(b + bh) * DIMD + k];
    __syncthreads();
    float acc = b1[k];
    const float* qq = &qrs[bh * 128];
    const float* wr = &w1b[k * 132];
    #pragma unroll
    for (int d = 0; d < 128; d += 4) {
      float4 wv = *reinterpret_cast<const float4*>(wr + d);
      float4 qv = *reinterpret_cast<const float4*>(qq + d);
      acc = fmaf(wv.x, qv.x, acc); acc = fmaf(wv.y, qv.y, acc);
      acc = fmaf(wv.z, qv.z, acc); acc = fmaf(wv.w, qv.w, acc);
    }
    qproj[(size_t)(b + bh) * DIMD + k] = acc;
    __syncthreads();
  }
}

// ---------------------------------------------------------------------------
// Main kernel: 512 blocks x 512 threads (8 waves), each wave owns ONE b.
// R17's verified operand-swap body + the ONE untried lever: the refer_embs
// (ev) stream flows through __builtin_amdgcn_global_load_lds into a wave-
// private 8 KB LDS buffer, issued one iteration ahead. gload consumes ZERO
// VGPRs -> in-flight bytes per wave jump from ~0.4 KB (the 128-VGPR-bound
// ceiling behind the 1.57 TB/s, 130-us invariant of R1-R17) to ~8.5 KB.
// m173 pre-swizzled-SOURCE trick: LDS dest stays linear (gload requirement);
// each lane's GLOBAL address carries the chunk-XOR (j ^ ((row&7)<<1)) so the
// GEMM2-side ev ds_reads land ~4-way instead of 16-way conflicted.
// Bias rv values are unpacked from the saved GEMM1 af bf16 packs (kills the
// bp[16] array; one extra bf16 rounding, inside threshold). sv is depth-1
// pipelined across GEMM2 groups. ONE vmcnt(0) consume-drain per iteration,
// after GEMM1 (~500 cy coverage); lgkmcnt(0) before each gload batch keeps
// the single-buffer hazard closed. LDS = 32 (W1a) + 32 (W2) + 64 (ebuf)
// = 128 KB. Bare __launch_bounds__(512) (never-spilled family).
// ---------------------------------------------------------------------------
__global__ __launch_bounds__(512) void main_kernel(
    const float* __restrict__ query_emb,
    const float* __restrict__ refer_embs, const float* __restrict__ refer_r,
    const float* __restrict__ start_embs, const float* __restrict__ b2,
    const float* __restrict__ qproj, const unsigned short* __restrict__ w1a_t,
    const unsigned short* __restrict__ w2_t, float* __restrict__ out)
{
  __shared__ unsigned short lds_w1a[128 * 128];   // 32 KB
  __shared__ unsigned short lds_w2[128 * 128];    // 32 KB
  __shared__ float ebuf[8][16 * 128];             // 8 KB per wave

  const int tid  = threadIdx.x;
  const int wave = tid >> 6;
  const int lane = tid & 63;
  const int g    = lane >> 4;   // 0..3
  const int c    = lane & 15;   // r-lane / weight-row-lane

  { // stage weight tables (linear uint4 copy; layout pre-applied in ws)
    const uint4* s1 = reinterpret_cast<const uint4*>(w1a_t);
    const uint4* s2 = reinterpret_cast<const uint4*>(w2_t);
    uint4* d1 = reinterpret_cast<uint4*>(lds_w1a);
    uint4* d2 = reinterpret_cast<uint4*>(lds_w2);
    #pragma unroll
    for (int i = 0; i < 4; ++i) {
      d1[tid + 512 * i] = s1[tid + 512 * i];
      d2[tid + 512 * i] = s2[tid + 512 * i];
    }
  }
  __syncthreads();   // the ONLY barrier

  const int swc = (c & 7) << 3;
  const int b = blockIdx.x * 8 + wave;  // this wave's b
  float* myeb = &ebuf[wave][0];

  // gload lane geometry: instr k covers rows {2k, 2k+1}; lane -> row
  // 2k+(lane>>5), 16B-chunk j=lane&31, SOURCE chunk pre-swizzled.
  const int rhalf = lane >> 5;          // 0 or 1
  const int jch   = lane & 31;

#define GLOADE(itv) do {                                                      \
    _Pragma("unroll")                                                         \
    for (int k_ = 0; k_ < 8; ++k_) {                                          \
      const int r_  = 2 * k_ + rhalf;                                         \
      const int ch_ = jch ^ ((r_ & 7) << 1);                                  \
      const float* gs_ = refer_embs +                                         \
          ((size_t)b * RR + (itv) * 16 + r_) * DIMD + ch_ * 4;                \
      GLD16(gs_, myeb + k_ * 256);                                            \
    }                                                                         \
  } while (0)

  f32x4 acc[8];
  #pragma unroll
  for (int nt = 0; nt < 8; ++nt) acc[nt] = (f32x4){0.f, 0.f, 0.f, 0.f};

  union U16x8 { unsigned int u[4]; s16x8 v; };

  GLOADE(0);   // prologue: ev tile for it=0 in flight (no VGPRs consumed)

  for (int it = 0; it < 4; ++it) {
    const size_t rowoff = ((size_t)b * RR + it * 16 + c) * DIMD + 4 * g;
    const float* rp = refer_r    + rowoff;
    const float* sp = start_embs + rowoff;

    // sv group-0 issued early (latency covered by GEMM1)
    float4 svA = *reinterpret_cast<const float4*>(sp);
    float4 svB = *reinterpret_cast<const float4*>(sp + 16);

    // ---- GEMM1: Ch[k=16nt+4g+reg, r=c] = W1a x rr + qproj
    f32x4 Ch[8];
    #pragma unroll
    for (int nt = 0; nt < 8; ++nt)
      Ch[nt] = *reinterpret_cast<const f32x4*>(qproj + (size_t)b * DIMD + 16 * nt + 4 * g);

    U16x8 afq[4];   // saved: GEMM2 bias unpacks rv from these
    #pragma unroll
    for (int ck = 0; ck < 4; ++ck) {
      const float4 rv0 = *reinterpret_cast<const float4*>(rp + 32 * ck);
      const float4 rv1 = *reinterpret_cast<const float4*>(rp + 32 * ck + 16);
      afq[ck].u[0] = pk2(rv0.x, rv0.y); afq[ck].u[1] = pk2(rv0.z, rv0.w);
      afq[ck].u[2] = pk2(rv1.x, rv1.y); afq[ck].u[3] = pk2(rv1.z, rv1.w);
      #pragma unroll
      for (int nt = 0; nt < 8; ++nt) {
        s16x8 wf = *reinterpret_cast<const s16x8*>(
            &lds_w1a[(nt * 16 + c) * DIMD + ((ck * 32 + g * 8) ^ swc)]);
        Ch[nt] = __builtin_amdgcn_mfma_f32_16x16x32_bf16(wf, afq[ck].v, Ch[nt], 0, 0, 0);
      }
      __builtin_amdgcn_sched_barrier(0);
    }

    // ---- relu + pack h (in-lane; layout matches GEMM2 B-frag)
    unsigned int hpk[16];
    #pragma unroll
    for (int nt = 0; nt < 8; ++nt) {
      hpk[2 * nt + 0] = pk2(fmaxf(Ch[nt][0], 0.f), fmaxf(Ch[nt][1], 0.f));
      hpk[2 * nt + 1] = pk2(fmaxf(Ch[nt][2], 0.f), fmaxf(Ch[nt][3], 0.f));
    }

    // ---- consume-drain: ev gload batch (and sv0) guaranteed landed
    asm volatile("s_waitcnt vmcnt(0)" ::: "memory");
    __builtin_amdgcn_sched_barrier(0);

    // ---- GEMM2 in 2-nt output groups; bias folded in from ebuf/sv/afq
    const int swz2 = (c & 7) << 1;
    #pragma unroll
    for (int ntg = 0; ntg < 4; ++ntg) {
      f32x4 Ca0 = *reinterpret_cast<const f32x4*>(b2 + 32 * ntg + 4 * g);
      f32x4 Ca1 = *reinterpret_cast<const f32x4*>(b2 + 32 * ntg + 16 + 4 * g);
      #pragma unroll
      for (int ck = 0; ck < 4; ++ck) {
        U16x8 hf;
        hf.u[0] = hpk[4 * ck + 0]; hf.u[1] = hpk[4 * ck + 1];
        hf.u[2] = hpk[4 * ck + 2]; hf.u[3] = hpk[4 * ck + 3];
        s16x8 w0 = *reinterpret_cast<const s16x8*>(
            &lds_w2[((2 * ntg) * 16 + c) * DIMD + ((ck * 32 + g * 8) ^ swc)]);
        s16x8 w1 = *reinterpret_cast<const s16x8*>(
            &lds_w2[((2 * ntg + 1) * 16 + c) * DIMD + ((ck * 32 + g * 8) ^ swc)]);
        Ca0 = __builtin_amdgcn_mfma_f32_16x16x32_bf16(w0, hf.v, Ca0, 0, 0, 0);
        Ca1 = __builtin_amdgcn_mfma_f32_16x16x32_bf16(w1, hf.v, Ca1, 0, 0, 0);
      }
      // depth-1 sv prefetch for next group
      float4 svAn, svBn;
      if (ntg < 3) {
        svAn = *reinterpret_cast<const float4*>(sp + 32 * (ntg + 1));
        svBn = *reinterpret_cast<const float4*>(sp + 32 * (ntg + 1) + 16);
      }
      // ev from swizzled LDS tile (linear dest + pre-swizzled source)
      const f32x4 ev0 = *reinterpret_cast<const f32x4*>(
          &myeb[c * 128 + ((8 * ntg + g) ^ swz2) * 4]);
      const f32x4 ev1 = *reinterpret_cast<const f32x4*>(
          &myeb[c * 128 + ((8 * ntg + 4 + g) ^ swz2) * 4]);
      // rv unpacked from saved af bf16 pack (quarter ck == ntg)
      acc[2 * ntg][0] = fmaf(Ca0[0], ev0[0] - svA.x - bflo(afq[ntg].u[0]), acc[2 * ntg][0]);
      acc[2 * ntg][1] = fmaf(Ca0[1], ev0[1] - svA.y - bfhi(afq[ntg].u[0]), acc[2 * ntg][1]);
      acc[2 * ntg][2] = fmaf(Ca0[2], ev0[2] - svA.z - bflo(afq[ntg].u[1]), acc[2 * ntg][2]);
      acc[2 * ntg][3] = fmaf(Ca0[3], ev0[3] - svA.w - bfhi(afq[ntg].u[1]), acc[2 * ntg][3]);
      acc[2 * ntg + 1][0] = fmaf(Ca1[0], ev1[0] - svB.x - bflo(afq[ntg].u[2]), acc[2 * ntg + 1][0]);
      acc[2 * ntg + 1][1] = fmaf(Ca1[1], ev1[1] - svB.y - bfhi(afq[ntg].u[2]), acc[2 * ntg + 1][1]);
      acc[2 * ntg + 1][2] = fmaf(Ca1[2], ev1[2] - svB.z - bflo(afq[ntg].u[3]), acc[2 * ntg + 1][2]);
      acc[2 * ntg + 1][3] = fmaf(Ca1[3], ev1[3] - svB.w - bfhi(afq[ntg].u[3]), acc[2 * ntg + 1][3]);
      svA = svAn; svB = svBn;
      __builtin_amdgcn_sched_barrier(0);
    }

    // ---- single-buffer hazard close + next iteration's ev batch
    if (it < 3) {
      asm volatile("s_waitcnt lgkmcnt(0)" ::: "memory");  // ev reads retired
      __builtin_amdgcn_sched_barrier(0);
      GLOADE(it + 1);
    }
  }
#undef GLOADE

  // ---- r-sum butterfly over the 16 c-lanes (once per b)
  #pragma unroll
  for (int mask = 1; mask <= 8; mask <<= 1)
    #pragma unroll
    for (int nt = 0; nt < 8; ++nt) {
      acc[nt][0] += __shfl_xor(acc[nt][0], mask);
      acc[nt][1] += __shfl_xor(acc[nt][1], mask);
      acc[nt][2] += __shfl_xor(acc[nt][2], mask);
      acc[nt][3] += __shfl_xor(acc[nt][3], mask);
    }

  // ---- epilogue: lanes c==0 (4 lanes, g=0..3) write d=16nt+4g..+3
  if (c == 0) {
    #pragma unroll
    for (int nt = 0; nt < 8; ++nt) {
      const size_t o = (size_t)b * DIMD + 16 * nt + 4 * g;
      const float4 qe = *reinterpret_cast<const float4*>(query_emb + o);
      float4 r;
      r.x = qe.x + acc[nt][0]; r.y = qe.y + acc[nt][1];
      r.z = qe.z + acc[nt][2]; r.w = qe.w + acc[nt][3];
      *reinterpret_cast<float4*>(out + o) = r;
    }
  }
}

extern "C" void kernel_launch(void* const* d_in, const int* in_sizes, int n_in,
                              void* d_out, int out_size, void* d_ws, size_t ws_size,
                              hipStream_t stream) {
  const float* query_emb  = (const float*)d_in[0];
  const float* offset_emb = (const float*)d_in[1];
  const float* refer_embs = (const float*)d_in[2];
  const float* query_r    = (const float*)d_in[3];
  const float* refer_r    = (const float*)d_in[4];
  const float* start_embs = (const float*)d_in[5];
  const float* W1 = (const float*)d_in[6];
  const float* b1 = (const float*)d_in[7];
  const float* W2 = (const float*)d_in[8];
  const float* b2 = (const float*)d_in[9];
  float* out = (float*)d_out;

  float* qproj = (float*)d_ws;                       // 4096*128 f32 = 2 MB
  unsigned short* w1a_t =
      (unsigned short*)((char*)d_ws + (size_t)BTOT * DIMD * sizeof(float));
  unsigned short* w2_t = w1a_t + 128 * 128;          // +32 KB each

  hipLaunchKernelGGL(prep_kernel, dim3(512), dim3(256), 0, stream,
                     W1, b1, query_r, W2, offset_emb, qproj, w1a_t, w2_t, out);
  hipLaunchKernelGGL(main_kernel, dim3(512), dim3(512), 0, stream,
                     query_emb, refer_embs, refer_r, start_embs,
                     b2, qproj, w1a_t, w2_t, out);
}

// Round 20
// 114.182 us; speedup vs baseline: 2.6756x; 2.6756x over previous
//
#include <hip/hip_runtime.h>
#include <hip/hip_bf16.h>
#include <stdint.h>

#define BTOT 4096
#define RR   64
#define DIMD 128

typedef short s16x8 __attribute__((ext_vector_type(8)));
typedef float f32x4 __attribute__((ext_vector_type(4)));

__device__ __forceinline__ unsigned short f2bf(float x) {
  __hip_bfloat16 h = __float2bfloat16(x);
  return __builtin_bit_cast(unsigned short, h);
}
__device__ __forceinline__ unsigned int pk2(float lo, float hi) {
  return ((unsigned int)f2bf(hi) << 16) | (unsigned int)f2bf(lo);
}
__device__ __forceinline__ float bflo(unsigned int u) {
  return __builtin_bit_cast(float, u << 16);
}
__device__ __forceinline__ float bfhi(unsigned int u) {
  return __builtin_bit_cast(float, u & 0xFFFF0000u);
}

// global -> LDS direct load, 16B per lane, no VGPR transit
#define GLD16(gsrc, ldst)                                                   \
  __builtin_amdgcn_global_load_lds(                                         \
      (const __attribute__((address_space(1))) void*)(gsrc),                \
      (__attribute__((address_space(3))) void*)(ldst), 16, 0, 0)

// ---------------------------------------------------------------------------
// Pre-kernel: qproj[b,k] = sum_d query_r[b,d]*W1[k,128+d] + b1[k]  (fp32),
// offset_emb passthrough, and blocks 0/1 emit PERMUTED+swizzled bf16 copies
// of W1a / W2 into ws. d-permutation pi(s) = 32*(s>>5) + 16*((s>>2)&1) +
// 4*((s>>3)&3) + (s&3); bank-XOR: addr = k*128 + (s ^ ((k&7)<<3)).
// [layout verified: R16/R17/R19 passed absmax 0.5]
// ---------------------------------------------------------------------------
__global__ __launch_bounds__(256) void prep_kernel(
    const float* __restrict__ W1, const float* __restrict__ b1,
    const float* __restrict__ query_r, const float* __restrict__ W2,
    const float* __restrict__ offset_emb,
    float* __restrict__ qproj, unsigned short* __restrict__ w1a_t,
    unsigned short* __restrict__ w2_t, float* __restrict__ out)
{
  __shared__ float w1b[128 * 132];   // +4 pad
  __shared__ float qrs[256];
  const int tid = threadIdx.x;

  { // offset_emb passthrough (1 float4 per thread; 512 blocks cover 4096x128)
    const size_t ob = (size_t)blockIdx.x * 8 * DIMD + (size_t)tid * 4;
    *reinterpret_cast<float4*>(out + (size_t)BTOT * DIMD + ob) =
        *reinterpret_cast<const float4*>(offset_emb + ob);
  }
  { // stage W1b fp32 into padded LDS
    const int k = tid >> 1, d0 = (tid & 1) * 64;
    const float* src = W1 + k * 256 + 128 + d0;
    float* dst = &w1b[k * 132 + d0];
    #pragma unroll
    for (int i = 0; i < 64; i += 4)
      *reinterpret_cast<float4*>(dst + i) = *reinterpret_cast<const float4*>(src + i);
  }
  if (blockIdx.x < 2) { // permuted + swizzled bf16 weight tables
    const float* Wsrc = (blockIdx.x == 0) ? W1 : W2;
    unsigned short* dstw = (blockIdx.x == 0) ? w1a_t : w2_t;
    const int stride = (blockIdx.x == 0) ? 256 : 128;
    for (int i = tid; i < 128 * 128; i += 256) {
      const int k = i >> 7, s = i & 127;
      const int d = 32 * (s >> 5) + 16 * ((s >> 2) & 1) + 4 * ((s >> 3) & 3) + (s & 3);
      dstw[k * 128 + (s ^ ((k & 7) << 3))] = f2bf(Wsrc[k * stride + d]);
    }
  }
  __syncthreads();

  const int b0 = blockIdx.x * 8;
  const int k = tid & 127, bh = tid >> 7;
  for (int p = 0; p < 4; ++p) {
    const int b = b0 + p * 2;
    qrs[tid] = query_r[(size_t)(b + bh) * DIMD + k];
    __syncthreads();
    float acc = b1[k];
    const float* qq = &qrs[bh * 128];
    const float* wr = &w1b[k * 132];
    #pragma unroll
    for (int d = 0; d < 128; d += 4) {
      float4 wv = *reinterpret_cast<const float4*>(wr + d);
      float4 qv = *reinterpret_cast<const float4*>(qq + d);
      acc = fmaf(wv.x, qv.x, acc); acc = fmaf(wv.y, qv.y, acc);
      acc = fmaf(wv.z, qv.z, acc); acc = fmaf(wv.w, qv.w, acc);
    }
    qproj[(size_t)(b + bh) * DIMD + k] = acc;
    __syncthreads();
  }
}

// ---------------------------------------------------------------------------
// Main kernel: 512 blocks x 512 threads (8 waves), each wave owns ONE b.
// R19 proved the gload_lds lever (delivered BW 1.57 -> 3.1 TB/s: zero-VGPR
// loads lift the in-flight-bytes cap) but spilled 447 MB (liveness ~140 >
// 128 cap). This round keeps the lever on a REGISTER DIET:
//  - ev (refer_embs) streams via global_load_lds into a wave-private 8 KB
//    LDS tile, one iteration ahead; pre-swizzled SOURCE address (m173) so
//    GEMM2-side ds_reads are bank-spread (scheme verified in R19).
//  - NO afq persistence / NO sv prefetch regs (the R19 spill): GEMM1 packs
//    psum[16] = bf16(sv+rv) -- exactly replaces R17's bp[16], net-zero
//    registers; GEMM2 bias = ev_f32 - unpack(psum).
//  - One vmcnt(0) per iter after GEMM1 (32 MFMAs cover gload latency);
//    one lgkmcnt(0) before each GLOADE refill (single-buffer hazard).
// Peak liveness ~105 (GEMM1) / ~90 (GEMM2) -- inside the proven 128 cap.
// LDS = 32 (W1a) + 32 (W2) + 8 x 8 (ebuf) = 128 KB. Bare
// __launch_bounds__(512) (never-spilled family).
// ---------------------------------------------------------------------------
__global__ __launch_bounds__(512) void main_kernel(
    const float* __restrict__ query_emb,
    const float* __restrict__ refer_embs, const float* __restrict__ refer_r,
    const float* __restrict__ start_embs, const float* __restrict__ b2,
    const float* __restrict__ qproj, const unsigned short* __restrict__ w1a_t,
    const unsigned short* __restrict__ w2_t, float* __restrict__ out)
{
  __shared__ unsigned short lds_w1a[128 * 128];   // 32 KB
  __shared__ unsigned short lds_w2[128 * 128];    // 32 KB
  __shared__ float ebuf[8][16 * 128];             // 8 KB per wave

  const int tid  = threadIdx.x;
  const int wave = tid >> 6;
  const int lane = tid & 63;
  const int g    = lane >> 4;   // 0..3
  const int c    = lane & 15;   // r-lane / weight-row-lane

  { // stage weight tables (linear uint4 copy; layout pre-applied in ws)
    const uint4* s1 = reinterpret_cast<const uint4*>(w1a_t);
    const uint4* s2 = reinterpret_cast<const uint4*>(w2_t);
    uint4* d1 = reinterpret_cast<uint4*>(lds_w1a);
    uint4* d2 = reinterpret_cast<uint4*>(lds_w2);
    #pragma unroll
    for (int i = 0; i < 4; ++i) {
      d1[tid + 512 * i] = s1[tid + 512 * i];
      d2[tid + 512 * i] = s2[tid + 512 * i];
    }
  }
  __syncthreads();   // the ONLY barrier

  const int swc = (c & 7) << 3;
  const int b = blockIdx.x * 8 + wave;  // this wave's b
  float* myeb = &ebuf[wave][0];

  // gload lane geometry: instr k covers rows {2k, 2k+1}; lane -> row
  // 2k+(lane>>5), 16B chunk j=lane&31, SOURCE chunk pre-swizzled.
  const int rhalf = lane >> 5;          // 0 or 1
  const int jch   = lane & 31;

#define GLOADE(itv) do {                                                      \
    _Pragma("unroll")                                                         \
    for (int k_ = 0; k_ < 8; ++k_) {                                          \
      const int r_  = 2 * k_ + rhalf;                                         \
      const int ch_ = jch ^ ((r_ & 7) << 1);                                  \
      const float* gs_ = refer_embs +                                         \
          ((size_t)b * RR + (itv) * 16 + r_) * DIMD + ch_ * 4;                \
      GLD16(gs_, myeb + k_ * 256);                                            \
    }                                                                         \
  } while (0)

  f32x4 acc[8];
  #pragma unroll
  for (int nt = 0; nt < 8; ++nt) acc[nt] = (f32x4){0.f, 0.f, 0.f, 0.f};

  union U16x8 { unsigned int u[4]; s16x8 v; };

  GLOADE(0);   // prologue: ev tile for it=0 in flight (no VGPRs consumed)

  for (int it = 0; it < 4; ++it) {
    const size_t rowoff = ((size_t)b * RR + it * 16 + c) * DIMD + 4 * g;
    const float* rp = refer_r    + rowoff;
    const float* sp = start_embs + rowoff;

    unsigned int psum[16];   // bf16-packed (sv + rv), consumed in GEMM2

    // ---- GEMM1: Ch[k=16nt+4g+reg, r=c] = W1a x rr + qproj
    f32x4 Ch[8];
    #pragma unroll
    for (int nt = 0; nt < 8; ++nt)
      Ch[nt] = *reinterpret_cast<const f32x4*>(qproj + (size_t)b * DIMD + 16 * nt + 4 * g);

    #pragma unroll
    for (int ck = 0; ck < 4; ++ck) {
      // per-quarter loads (4 float4 transient: rv x2, sv x2; die this ck)
      const float4 rv0 = *reinterpret_cast<const float4*>(rp + 32 * ck);
      const float4 rv1 = *reinterpret_cast<const float4*>(rp + 32 * ck + 16);
      const float4 sv0 = *reinterpret_cast<const float4*>(sp + 32 * ck);
      const float4 sv1 = *reinterpret_cast<const float4*>(sp + 32 * ck + 16);
      U16x8 af;
      af.u[0] = pk2(rv0.x, rv0.y); af.u[1] = pk2(rv0.z, rv0.w);
      af.u[2] = pk2(rv1.x, rv1.y); af.u[3] = pk2(rv1.z, rv1.w);
      psum[4 * ck + 0] = pk2(sv0.x + rv0.x, sv0.y + rv0.y);
      psum[4 * ck + 1] = pk2(sv0.z + rv0.z, sv0.w + rv0.w);
      psum[4 * ck + 2] = pk2(sv1.x + rv1.x, sv1.y + rv1.y);
      psum[4 * ck + 3] = pk2(sv1.z + rv1.z, sv1.w + rv1.w);
      #pragma unroll
      for (int nt = 0; nt < 8; ++nt) {
        s16x8 wf = *reinterpret_cast<const s16x8*>(
            &lds_w1a[(nt * 16 + c) * DIMD + ((ck * 32 + g * 8) ^ swc)]);
        Ch[nt] = __builtin_amdgcn_mfma_f32_16x16x32_bf16(wf, af.v, Ch[nt], 0, 0, 0);
      }
      __builtin_amdgcn_sched_barrier(0);   // bound hoisting to one quarter
    }

    // ---- relu + pack h (in-lane; layout matches GEMM2 B-frag)
    unsigned int hpk[16];
    #pragma unroll
    for (int nt = 0; nt < 8; ++nt) {
      hpk[2 * nt + 0] = pk2(fmaxf(Ch[nt][0], 0.f), fmaxf(Ch[nt][1], 0.f));
      hpk[2 * nt + 1] = pk2(fmaxf(Ch[nt][2], 0.f), fmaxf(Ch[nt][3], 0.f));
    }

    // ---- consume-drain: the ev gload batch has landed
    asm volatile("s_waitcnt vmcnt(0)" ::: "memory");
    __builtin_amdgcn_sched_barrier(0);

    // ---- GEMM2 in 2-nt output groups; bias = ev(LDS) - unpack(psum)
    const int swz2 = (c & 7) << 1;
    #pragma unroll
    for (int ntg = 0; ntg < 4; ++ntg) {
      f32x4 Ca0 = *reinterpret_cast<const f32x4*>(b2 + 32 * ntg + 4 * g);
      f32x4 Ca1 = *reinterpret_cast<const f32x4*>(b2 + 32 * ntg + 16 + 4 * g);
      #pragma unroll
      for (int ck = 0; ck < 4; ++ck) {
        U16x8 hf;
        hf.u[0] = hpk[4 * ck + 0]; hf.u[1] = hpk[4 * ck + 1];
        hf.u[2] = hpk[4 * ck + 2]; hf.u[3] = hpk[4 * ck + 3];
        s16x8 w0 = *reinterpret_cast<const s16x8*>(
            &lds_w2[((2 * ntg) * 16 + c) * DIMD + ((ck * 32 + g * 8) ^ swc)]);
        s16x8 w1 = *reinterpret_cast<const s16x8*>(
            &lds_w2[((2 * ntg + 1) * 16 + c) * DIMD + ((ck * 32 + g * 8) ^ swc)]);
        Ca0 = __builtin_amdgcn_mfma_f32_16x16x32_bf16(w0, hf.v, Ca0, 0, 0, 0);
        Ca1 = __builtin_amdgcn_mfma_f32_16x16x32_bf16(w1, hf.v, Ca1, 0, 0, 0);
      }
      // ev from the pre-swizzled wave tile (layout verified in R19)
      const f32x4 ev0 = *reinterpret_cast<const f32x4*>(
          &myeb[c * 128 + ((8 * ntg + g) ^ swz2) * 4]);
      const f32x4 ev1 = *reinterpret_cast<const f32x4*>(
          &myeb[c * 128 + ((8 * ntg + 4 + g) ^ swz2) * 4]);
      acc[2 * ntg][0] = fmaf(Ca0[0], ev0[0] - bflo(psum[4 * ntg + 0]), acc[2 * ntg][0]);
      acc[2 * ntg][1] = fmaf(Ca0[1], ev0[1] - bfhi(psum[4 * ntg + 0]), acc[2 * ntg][1]);
      acc[2 * ntg][2] = fmaf(Ca0[2], ev0[2] - bflo(psum[4 * ntg + 1]), acc[2 * ntg][2]);
      acc[2 * ntg][3] = fmaf(Ca0[3], ev0[3] - bfhi(psum[4 * ntg + 1]), acc[2 * ntg][3]);
      acc[2 * ntg + 1][0] = fmaf(Ca1[0], ev1[0] - bflo(psum[4 * ntg + 2]), acc[2 * ntg + 1][0]);
      acc[2 * ntg + 1][1] = fmaf(Ca1[1], ev1[1] - bfhi(psum[4 * ntg + 2]), acc[2 * ntg + 1][1]);
      acc[2 * ntg + 1][2] = fmaf(Ca1[2], ev1[2] - bflo(psum[4 * ntg + 3]), acc[2 * ntg + 1][2]);
      acc[2 * ntg + 1][3] = fmaf(Ca1[3], ev1[3] - bfhi(psum[4 * ntg + 3]), acc[2 * ntg + 1][3]);
      __builtin_amdgcn_sched_barrier(0);
    }

    // ---- single-buffer hazard close + next iteration's ev batch
    if (it < 3) {
      asm volatile("s_waitcnt lgkmcnt(0)" ::: "memory");  // ev reads retired
      __builtin_amdgcn_sched_barrier(0);
      GLOADE(it + 1);
    }
  }
#undef GLOADE

  // ---- r-sum butterfly over the 16 c-lanes (once per b)
  #pragma unroll
  for (int mask = 1; mask <= 8; mask <<= 1)
    #pragma unroll
    for (int nt = 0; nt < 8; ++nt) {
      acc[nt][0] += __shfl_xor(acc[nt][0], mask);
      acc[nt][1] += __shfl_xor(acc[nt][1], mask);
      acc[nt][2] += __shfl_xor(acc[nt][2], mask);
      acc[nt][3] += __shfl_xor(acc[nt][3], mask);
    }

  // ---- epilogue: lanes c==0 (4 lanes, g=0..3) write d=16nt+4g..+3
  if (c == 0) {
    #pragma unroll
    for (int nt = 0; nt < 8; ++nt) {
      const size_t o = (size_t)b * DIMD + 16 * nt + 4 * g;
      const float4 qe = *reinterpret_cast<const float4*>(query_emb + o);
      float4 r;
      r.x = qe.x + acc[nt][0]; r.y = qe.y + acc[nt][1];
      r.z = qe.z + acc[nt][2]; r.w = qe.w + acc[nt][3];
      *reinterpret_cast<float4*>(out + o) = r;
    }
  }
}

extern "C" void kernel_launch(void* const* d_in, const int* in_sizes, int n_in,
                              void* d_out, int out_size, void* d_ws, size_t ws_size,
                              hipStream_t stream) {
  const float* query_emb  = (const float*)d_in[0];
  const float* offset_emb = (const float*)d_in[1];
  const float* refer_embs = (const float*)d_in[2];
  const float* query_r    = (const float*)d_in[3];
  const float* refer_r    = (const float*)d_in[4];
  const float* start_embs = (const float*)d_in[5];
  const float* W1 = (const float*)d_in[6];
  const float* b1 = (const float*)d_in[7];
  const float* W2 = (const float*)d_in[8];
  const float* b2 = (const float*)d_in[9];
  float* out = (float*)d_out;

  float* qproj = (float*)d_ws;                       // 4096*128 f32 = 2 MB
  unsigned short* w1a_t =
      (unsigned short*)((char*)d_ws + (size_t)BTOT * DIMD * sizeof(float));
  unsigned short* w2_t = w1a_t + 128 * 128;          // +32 KB each

  hipLaunchKernelGGL(prep_kernel, dim3(512), dim3(256), 0, stream,
                     W1, b1, query_r, W2, offset_emb, qproj, w1a_t, w2_t, out);
  hipLaunchKernelGGL(main_kernel, dim3(512), dim3(512), 0, stream,
                     query_emb, refer_embs, refer_r, start_embs,
                     b2, qproj, w1a_t, w2_t, out);
}